// Round 10
// baseline (421.966 us; speedup 1.0000x reference)
//
#include <hip/hip_runtime.h>
#include <math.h>

#define CCH 512
#define F1 25088      // 512*49
#define FC 4096
#define NCLS 1000
#define OW 224
#define KSPLIT 8
#define KSL 512       // FC/KSPLIT
#define PSTRIDE (CCH*FC)   // one bf16 partial plane (ushort elems)

// ws float offsets
#define WS_DT 0                          // [4096][512] f32
#define WS_MP (WS_DT + FC*CCH)           // 25088
#define WS_H1PRE (WS_MP + F1)            // 4096
#define WS_H1 (WS_H1PRE + FC)            // 4096
#define WS_H2 (WS_H1 + FC)               // 4096 (fallback)
#define WS_H2PART (WS_H2 + FC)           // [8][4096]
#define WS_LOGITS (WS_H2PART + 8*FC)     // 1000
#define WS_CLSBASE (WS_LOGITS + NCLS)    // 2
#define WS_ALPHA (WS_CLSBASE + 2)        // 512
#define WS_MINMAX (WS_ALPHA + CCH)       // 2 ints (fallback)
#define WS_CNT (WS_MINMAX + 2)           // 2 ints: election counters
#define WS_LOGPART (WS_CNT + 2)          // [64][512] (fallback)
#define WS_A (WS_LOGPART + 64*CCH)       // bf16 [512][4096]
#define WS_PARTB (WS_A + CCH*FC/2)       // bf16 [8][512][4096]
#define WS_END (WS_PARTB + KSPLIT*CCH*FC/2)
#define WS_NEED_BYTES ((size_t)WS_END * 4)

typedef __attribute__((ext_vector_type(8))) short bfrag;
typedef __attribute__((ext_vector_type(4))) float f32x4;

static __device__ __forceinline__ unsigned short f2bf(float x) {
    unsigned u = __float_as_uint(x);
    unsigned r = 0x7FFFu + ((u >> 16) & 1u);
    return (unsigned short)((u + r) >> 16);
}

#define GLD16(g, l) __builtin_amdgcn_global_load_lds( \
    (const __attribute__((address_space(1))) void*)(g), \
    (__attribute__((address_space(3))) void*)(l), 16, 0, 0)

// -------- maxpool 2x2 (+ init minmax + zero election counters) --------
__global__ void k_maxpool(const float* __restrict__ act, float* __restrict__ ws) {
    int t = threadIdx.x;
    if (blockIdx.x == 0) {
        if (t == 0) ((int*)(ws + WS_MINMAX))[0] = 0x7F800000;
        if (t == 1) ((int*)(ws + WS_MINMAX))[1] = 0;
        if (t == 2) ((int*)(ws + WS_CNT))[0] = 0;
        if (t == 3) ((int*)(ws + WS_CNT))[1] = 0;
    }
    int idx = blockIdx.x * 256 + t;
    if (idx >= CCH * 49) return;
    int c = idx / 49, r = idx % 49, y = r / 7, x = r % 7;
    const float* a = act + c * 196 + (2 * y) * 14 + 2 * x;
    float m = fmaxf(fmaxf(a[0], a[1]), fmaxf(a[14], a[15]));
    ws[WS_MP + idx] = m;
}

// -------- layer-1 partials + fused h1, batched loads --------
__global__ __launch_bounds__(256) void k_phi7(const float* __restrict__ W1,
                                              const float* __restrict__ mp,
                                              const float* __restrict__ b1,
                                              float* __restrict__ Dt,
                                              float* __restrict__ h1pre,
                                              float* __restrict__ h1) {
    __shared__ float buf[12544];
    __shared__ float red[256];
    int j = blockIdx.x, t = threadIdx.x;
    const float4* wrow = (const float4*)(W1 + (size_t)j * F1);
    const float4* mrow = (const float4*)mp;
    float sh = 0.f;
    #pragma unroll
    for (int h = 0; h < 2; ++h) {
        const float4* src = wrow + h * 3136;
        const float4* msc = mrow + h * 3136;
        __syncthreads();
        #pragma unroll
        for (int b = 0; b < 2; ++b) {
            float4 w[6], m[6];
            #pragma unroll
            for (int e = 0; e < 6; ++e) {
                int n = t + 256 * (b * 6 + e);
                w[e] = src[n]; m[e] = msc[n];
            }
            #pragma unroll
            for (int e = 0; e < 6; ++e) {
                int n = t + 256 * (b * 6 + e);
                float4 p;
                p.x = w[e].x * m[e].x; p.y = w[e].y * m[e].y;
                p.z = w[e].z * m[e].z; p.w = w[e].w * m[e].w;
                *(float4*)&buf[n * 4] = p;
            }
        }
        if (t < 64) {
            int n = 3072 + t;
            float4 w = src[n], m = msc[n];
            float4 p;
            p.x = w.x * m.x; p.y = w.y * m.y; p.z = w.z * m.z; p.w = w.w * m.w;
            *(float4*)&buf[n * 4] = p;
        }
        __syncthreads();
        const float* bb = buf + t * 49;
        float s = 0.f;
        #pragma unroll
        for (int k = 0; k < 49; ++k) s += bb[k];
        Dt[(size_t)j * CCH + h * 256 + t] = s;
        sh += s;
    }
    red[t] = sh;
    __syncthreads();
    if (t < 128) red[t] += red[t + 128];
    __syncthreads();
    if (t < 64) {
        float v = red[t] + red[t + 64];
        for (int off = 32; off > 0; off >>= 1) v += __shfl_down(v, off, 64);
        if (t == 0) { float hv = b1[j] + v; h1pre[j] = hv; h1[j] = fmaxf(hv, 0.f); }
    }
}

// -------- A[i][k] = relu(h1pre[k] - Dt[k][i]) in bf16, [512][4096] --------
__global__ __launch_bounds__(256) void k_abuild(const float* __restrict__ Dt,
                                                const float* __restrict__ h1pre,
                                                unsigned short* __restrict__ A) {
    __shared__ unsigned short tile[64][72];
    int kt = blockIdx.x, it = blockIdx.y, t = threadIdx.x;
    int k0 = kt * 64, i0 = it * 64;
    #pragma unroll
    for (int q = 0; q < 16; ++q) {
        int kk = q * 4 + (t >> 6);
        int ii = t & 63;
        float v = fmaxf(h1pre[k0 + kk] - Dt[(size_t)(k0 + kk) * CCH + i0 + ii], 0.f);
        tile[kk][ii] = f2bf(v);
    }
    __syncthreads();
    #pragma unroll
    for (int q = 0; q < 4; ++q) {
        int c = q * 256 + t;
        int ii = c >> 4, kc = c & 15;
        ushort4 v;
        v.x = tile[kc * 4 + 0][ii]; v.y = tile[kc * 4 + 1][ii];
        v.z = tile[kc * 4 + 2][ii]; v.w = tile[kc * 4 + 3][ii];
        *(ushort4*)&A[(size_t)(i0 + ii) * FC + k0 + kc * 4] = v;
    }
}

// -------- ablation GEMM v6 (r9-proven): double-buffered, 1 barrier/K-step --------
__global__ __launch_bounds__(512) void k_mfma_v6(
    const unsigned short* __restrict__ A, const float* __restrict__ W2,
    const float* __restrict__ h1, unsigned short* __restrict__ partb,
    float* __restrict__ h2part) {
    __shared__ char As[2][32768];
    __shared__ char Bs[2][4096];
    __shared__ float h1s[KSL];
    int bid = blockIdx.x;
    int ks = bid & 7, nj = bid >> 3;
    int t = threadIdx.x;
    int wid = t >> 6, lane = t & 63, lr = lane & 15, lh = lane >> 4;
    int j0 = nj * 64;
    int kb = ks * KSL;

    h1s[t] = h1[kb + t];
    __syncthreads();

    int brow = t >> 3, bkc = t & 7;
    const float* wsrc = W2 + (size_t)(j0 + brow) * FC + kb + bkc * 4;
    int bsw = (brow & 3) ^ ((brow >> 2) & 1);
    int boff = (brow * 4 + ((bkc >> 1) ^ bsw)) * 16 + (bkc & 1) * 8;

    float hacc = 0.f;
    f32x4 acc[4][4];
    #pragma unroll
    for (int f = 0; f < 4; ++f)
        #pragma unroll
        for (int n = 0; n < 4; ++n) acc[f][n] = (f32x4){0.f, 0.f, 0.f, 0.f};

    #pragma unroll
    for (int r = 0; r < 4; ++r) {
        int c = t + 512 * r;
        int row = c >> 2, ch = c & 3;
        int sw = (row & 3) ^ ((row >> 2) & 1);
        GLD16(A + (size_t)row * FC + kb + ((ch ^ sw) * 8), As[0] + (size_t)c * 16);
    }
    {
        float4 w = *(const float4*)wsrc;
        hacc += w.x * h1s[bkc * 4 + 0] + w.y * h1s[bkc * 4 + 1]
              + w.z * h1s[bkc * 4 + 2] + w.w * h1s[bkc * 4 + 3];
        ushort4 pk;
        pk.x = f2bf(w.x); pk.y = f2bf(w.y); pk.z = f2bf(w.z); pk.w = f2bf(w.w);
        *(ushort4*)(Bs[0] + boff) = pk;
    }
    __syncthreads();

    int cur = 0;
    for (int kst = 0; kst + 32 < KSL; kst += 32) {
        int nxt = kst + 32;
        #pragma unroll
        for (int r = 0; r < 4; ++r) {
            int c = t + 512 * r;
            int row = c >> 2, ch = c & 3;
            int sw = (row & 3) ^ ((row >> 2) & 1);
            GLD16(A + (size_t)row * FC + kb + nxt + ((ch ^ sw) * 8),
                  As[cur ^ 1] + (size_t)c * 16);
        }
        float4 w = *(const float4*)(wsrc + nxt);
        {
            bfrag bfr[4];
            #pragma unroll
            for (int n = 0; n < 4; ++n) {
                int br = n * 16 + lr;
                int swb = (br & 3) ^ ((br >> 2) & 1);
                bfr[n] = *(const bfrag*)(Bs[cur] + (br * 4 + (lh ^ swb)) * 16);
            }
            #pragma unroll
            for (int f = 0; f < 4; ++f) {
                int ar = wid * 64 + f * 16 + lr;
                int swa = (ar & 3) ^ ((ar >> 2) & 1);
                bfrag av = *(const bfrag*)(As[cur] + (ar * 4 + (lh ^ swa)) * 16);
                #pragma unroll
                for (int n = 0; n < 4; ++n)
                    acc[f][n] = __builtin_amdgcn_mfma_f32_16x16x32_bf16(av, bfr[n], acc[f][n], 0, 0, 0);
            }
        }
        hacc += w.x * h1s[nxt + bkc * 4 + 0] + w.y * h1s[nxt + bkc * 4 + 1]
              + w.z * h1s[nxt + bkc * 4 + 2] + w.w * h1s[nxt + bkc * 4 + 3];
        {
            ushort4 pk;
            pk.x = f2bf(w.x); pk.y = f2bf(w.y); pk.z = f2bf(w.z); pk.w = f2bf(w.w);
            *(ushort4*)(Bs[cur ^ 1] + boff) = pk;
        }
        __syncthreads();
        cur ^= 1;
    }
    {
        bfrag bfr[4];
        #pragma unroll
        for (int n = 0; n < 4; ++n) {
            int br = n * 16 + lr;
            int swb = (br & 3) ^ ((br >> 2) & 1);
            bfr[n] = *(const bfrag*)(Bs[cur] + (br * 4 + (lh ^ swb)) * 16);
        }
        #pragma unroll
        for (int f = 0; f < 4; ++f) {
            int ar = wid * 64 + f * 16 + lr;
            int swa = (ar & 3) ^ ((ar >> 2) & 1);
            bfrag av = *(const bfrag*)(As[cur] + (ar * 4 + (lh ^ swa)) * 16);
            #pragma unroll
            for (int n = 0; n < 4; ++n)
                acc[f][n] = __builtin_amdgcn_mfma_f32_16x16x32_bf16(av, bfr[n], acc[f][n], 0, 0, 0);
        }
    }

    hacc += __shfl_down(hacc, 4, 8);
    hacc += __shfl_down(hacc, 2, 8);
    hacc += __shfl_down(hacc, 1, 8);
    if (bkc == 0) h2part[ks * FC + j0 + brow] = hacc;

    unsigned short* pb = partb + (size_t)ks * PSTRIDE;
    #pragma unroll
    for (int f = 0; f < 4; ++f) {
        int row0 = wid * 64 + f * 16 + lh * 4;
        #pragma unroll
        for (int rr = 0; rr < 4; ++rr)
            #pragma unroll
            for (int n = 0; n < 4; ++n)
                pb[(size_t)(row0 + rr) * FC + j0 + n * 16 + lr] = f2bf(acc[f][n][rr]);
    }
}

// -------- tail1: h2(LDS) + W3 gemv + last-block argmax --------
__global__ __launch_bounds__(256) void k_tail1(
    const float* __restrict__ h2part, const float* __restrict__ b2,
    const float* __restrict__ W3, const float* __restrict__ b3,
    float* __restrict__ ws, float* __restrict__ out, int* __restrict__ counter) {
    __shared__ float h2s[FC];   // 16KB
    __shared__ float red[256];
    __shared__ int lastFlag;
    int j = blockIdx.x, t = threadIdx.x;
    #pragma unroll
    for (int q = 0; q < 16; ++q) {
        int jj = q * 256 + t;
        float v = b2[jj];
        #pragma unroll
        for (int p = 0; p < KSPLIT; ++p) v += h2part[p * FC + jj];
        h2s[jj] = fmaxf(v, 0.f);
    }
    __syncthreads();
    const float4* row = (const float4*)(W3 + (size_t)j * FC);
    const float4* hv = (const float4*)h2s;
    float s = 0.f;
    #pragma unroll
    for (int q = 0; q < 4; ++q) {
        int n = q * 256 + t;
        float4 w = row[n], x = hv[n];
        s += w.x * x.x + w.y * x.y + w.z * x.z + w.w * x.w;
    }
    red[t] = s; __syncthreads();
    if (t < 128) red[t] += red[t + 128]; __syncthreads();
    if (t < 64)  red[t] += red[t + 64];  __syncthreads();
    if (t < 64) {
        float x = red[t];
        for (int off = 32; off > 0; off >>= 1) x += __shfl_down(x, off, 64);
        if (t == 0) ws[WS_LOGITS + j] = x + b3[j];
    }
    // election
    __threadfence();
    if (t == 0) lastFlag = (atomicAdd(counter, 1) == NCLS - 1);
    __syncthreads();
    if (!lastFlag) return;
    __threadfence();
    // argmax over 1000 logits
    float best = -INFINITY; int bi = NCLS;
    for (int n = t; n < NCLS; n += 256) {
        float v = ws[WS_LOGITS + n];
        if (v > best || (v == best && n < bi)) { best = v; bi = n; }
    }
    __shared__ float bv[256]; __shared__ int bidx[256];
    bv[t] = best; bidx[t] = bi; __syncthreads();
    for (int o = 128; o > 0; o >>= 1) {
        if (t < o) {
            float v2 = bv[t + o]; int i2 = bidx[t + o];
            if (v2 > bv[t] || (v2 == bv[t] && i2 < bidx[t])) { bv[t] = v2; bidx[t] = i2; }
        }
        __syncthreads();
    }
    if (t == 0) {
        ws[WS_CLSBASE] = (float)bidx[0];
        ws[WS_CLSBASE + 1] = bv[0];
        out[50176] = (float)bidx[0];
    }
}

// -------- tail2: alpha + last-block (weighted+resize+minmax+norm) --------
__global__ __launch_bounds__(256) void k_tail2(
    const unsigned short* __restrict__ partb, const float* __restrict__ b2,
    const float* __restrict__ W3, const float* __restrict__ b3,
    const float* __restrict__ act, float* __restrict__ ws,
    float* __restrict__ out, int* __restrict__ counter) {
    __shared__ float red[256];
    __shared__ int lastFlag;
    int i = blockIdx.x, t = threadIdx.x;
    int cls = (int)ws[WS_CLSBASE]; float base = ws[WS_CLSBASE + 1];
    const float* w3r = W3 + (size_t)cls * FC;
    float s = 0.f;
    #pragma unroll
    for (int q = 0; q < 2; ++q) {
        int jj = (q * 256 + t) * 8;
        float acc8[8];
        #pragma unroll
        for (int e = 0; e < 8; ++e) acc8[e] = b2[jj + e];
        #pragma unroll
        for (int p = 0; p < KSPLIT; ++p) {
            uint4 pv = *(const uint4*)(partb + (size_t)p * PSTRIDE + (size_t)i * FC + jj);
            #pragma unroll
            for (int e = 0; e < 4; ++e) {
                unsigned a = ((const unsigned*)&pv)[e];
                acc8[e * 2]     += __uint_as_float(a << 16);
                acc8[e * 2 + 1] += __uint_as_float(a & 0xFFFF0000u);
            }
        }
        #pragma unroll
        for (int e = 0; e < 8; ++e) s += fmaxf(acc8[e], 0.f) * w3r[jj + e];
    }
    red[t] = s; __syncthreads();
    if (t < 128) red[t] += red[t + 128]; __syncthreads();
    if (t < 64)  red[t] += red[t + 64];  __syncthreads();
    if (t < 64) {
        float x = red[t];
        for (int off = 32; off > 0; off >>= 1) x += __shfl_down(x, off, 64);
        if (t == 0) ws[WS_ALPHA + i] = (base - (x + b3[cls])) / base;
    }
    // election
    __threadfence();
    if (t == 0) lastFlag = (atomicAdd(counter, 1) == CCH - 1);
    __syncthreads();
    if (!lastFlag) return;
    __threadfence();
    // weighted 14x14
    __shared__ float sA[CCH];
    __shared__ float sW[196];
    for (int c = t; c < CCH; c += 256) sA[c] = ws[WS_ALPHA + c];
    __syncthreads();
    if (t < 196) {
        float s2 = 0.f;
        for (int c = 0; c < CCH; ++c) s2 = fmaf(sA[c], act[c * 196 + t], s2);
        sW[t] = s2;
    }
    __syncthreads();
    // resize + relu + local minmax
    float mn = INFINITY, mx = -INFINITY;
    for (int pix = t; pix < 50176; pix += 256) {
        int y = pix / OW, x = pix % OW;
        float uy = (y + 0.5f) * 0.0625f - 0.5f;
        float ux = (x + 0.5f) * 0.0625f - 0.5f;
        float y0f = floorf(uy), x0f = floorf(ux);
        float fy = uy - y0f, fx = ux - x0f;
        int y0 = (int)y0f, x0 = (int)x0f;
        int y0c = min(max(y0, 0), 13), y1c = min(max(y0 + 1, 0), 13);
        int x0c = min(max(x0, 0), 13), x1c = min(max(x0 + 1, 0), 13);
        float v00 = sW[y0c * 14 + x0c], v01 = sW[y0c * 14 + x1c];
        float v10 = sW[y1c * 14 + x0c], v11 = sW[y1c * 14 + x1c];
        float v0 = v00 + (v01 - v00) * fx;
        float v1 = v10 + (v11 - v10) * fx;
        float v = v0 + (v1 - v0) * fy;
        float f = fmaxf(v, 0.f);
        out[pix] = f;
        mn = fminf(mn, f); mx = fmaxf(mx, f);
    }
    __shared__ float rmn[256], rmx[256];
    rmn[t] = mn; rmx[t] = mx; __syncthreads();
    for (int o = 128; o > 0; o >>= 1) {
        if (t < o) { rmn[t] = fminf(rmn[t], rmn[t + o]); rmx[t] = fmaxf(rmx[t], rmx[t + o]); }
        __syncthreads();
    }
    mn = rmn[0]; mx = rmx[0];
    if (mx != mn) {
        float inv = 1.f / (mx - mn);
        for (int pix = t; pix < 50176; pix += 256)
            out[pix] = (out[pix] - mn) * inv;
    }
}

// ======== fallback fp32 path (ws too small) ========
template <bool RELU>
__global__ void k_gemv4096(const float* __restrict__ M, const float* __restrict__ v,
                           const float* __restrict__ bias, float* __restrict__ out) {
    int j = blockIdx.x, t = threadIdx.x;
    const float4* row = (const float4*)(M + (size_t)j * FC);
    const float4* vv = (const float4*)v;
    float s = 0.f;
    #pragma unroll
    for (int q = 0; q < 4; ++q) {
        int n = q * 256 + t;
        float4 w = row[n], x = vv[n];
        s += w.x * x.x + w.y * x.y + w.z * x.z + w.w * x.w;
    }
    __shared__ float red[256];
    red[t] = s; __syncthreads();
    if (t < 128) red[t] += red[t + 128]; __syncthreads();
    if (t < 64)  red[t] += red[t + 64];  __syncthreads();
    if (t < 64) {
        float x = red[t];
        for (int off = 32; off > 0; off >>= 1) x += __shfl_down(x, off, 64);
        if (t == 0) { float r2 = bias[j] + x; out[j] = RELU ? fmaxf(r2, 0.f) : r2; }
    }
}

__global__ void k_argmax(const float* __restrict__ logits, float* __restrict__ clsbase,
                         float* __restrict__ dout_cls) {
    int t = threadIdx.x;
    float best = -INFINITY; int bi = NCLS;
    for (int n = t; n < NCLS; n += 256) {
        float v = logits[n];
        if (v > best || (v == best && n < bi)) { best = v; bi = n; }
    }
    __shared__ float bv[256]; __shared__ int bidx[256];
    bv[t] = best; bidx[t] = bi; __syncthreads();
    for (int o = 128; o > 0; o >>= 1) {
        if (t < o) {
            float v2 = bv[t + o]; int i2 = bidx[t + o];
            if (v2 > bv[t] || (v2 == bv[t] && i2 < bidx[t])) { bv[t] = v2; bidx[t] = i2; }
        }
        __syncthreads();
    }
    if (t == 0) { clsbase[0] = (float)bidx[0]; clsbase[1] = bv[0]; *dout_cls = (float)bidx[0]; }
}

__global__ __launch_bounds__(256) void k_gemm_abl(
    const float* __restrict__ Dt, const float* __restrict__ h1pre,
    const float* __restrict__ W2, const float* __restrict__ b2,
    const float* __restrict__ W3, const float* __restrict__ clsbase,
    float* __restrict__ logit_part) {
    int mi = blockIdx.x, nj = blockIdx.y, t = threadIdx.x;
    int tx = t & 15, ty = t >> 4;
    int i0 = mi * 64, j0 = nj * 64;
    __shared__ float As2[16][64];
    __shared__ float Bs2[16][65];
    float acc[4][4] = {};
    for (int k0 = 0; k0 < FC; k0 += 16) {
        #pragma unroll
        for (int r = 0; r < 4; ++r) {
            int e = t + 256 * r; int kk = e >> 6, ii = e & 63;
            As2[kk][ii] = fmaxf(h1pre[k0 + kk] - Dt[(size_t)(k0 + kk) * CCH + i0 + ii], 0.f);
        }
        {
            int jj = t >> 2, kks = (t & 3) * 4;
            const float4 wv = *(const float4*)(W2 + (size_t)(j0 + jj) * FC + k0 + kks);
            Bs2[kks + 0][jj] = wv.x; Bs2[kks + 1][jj] = wv.y;
            Bs2[kks + 2][jj] = wv.z; Bs2[kks + 3][jj] = wv.w;
        }
        __syncthreads();
        #pragma unroll
        for (int kk = 0; kk < 16; ++kk) {
            float4 a4 = *(const float4*)&As2[kk][tx * 4];
            float av[4] = {a4.x, a4.y, a4.z, a4.w};
            float bv[4] = {Bs2[kk][ty * 4 + 0], Bs2[kk][ty * 4 + 1],
                           Bs2[kk][ty * 4 + 2], Bs2[kk][ty * 4 + 3]};
            #pragma unroll
            for (int a = 0; a < 4; ++a)
                #pragma unroll
                for (int bb = 0; bb < 4; ++bb)
                    acc[a][bb] = fmaf(av[a], bv[bb], acc[a][bb]);
        }
        __syncthreads();
    }
    int cls = (int)clsbase[0];
    const float* w3r = W3 + (size_t)cls * FC;
    float prt[4] = {0.f, 0.f, 0.f, 0.f};
    #pragma unroll
    for (int bb = 0; bb < 4; ++bb) {
        int j2 = j0 + ty * 4 + bb;
        float b2v = b2[j2], w3 = w3r[j2];
        #pragma unroll
        for (int a = 0; a < 4; ++a) prt[a] = fmaf(fmaxf(acc[a][bb] + b2v, 0.f), w3, prt[a]);
    }
    __shared__ float red2[16][68];
    #pragma unroll
    for (int a = 0; a < 4; ++a) red2[ty][tx * 4 + a] = prt[a];
    __syncthreads();
    if (t < 64) {
        float s = 0.f;
        #pragma unroll
        for (int q = 0; q < 16; ++q) s += red2[q][t];
        logit_part[nj * CCH + i0 + t] = s;
    }
}

__global__ void k_alpha_fb(const float* __restrict__ logit_part, const float* __restrict__ b3,
                           const float* __restrict__ clsbase, float* __restrict__ alpha) {
    int t = blockIdx.x * 256 + threadIdx.x;
    if (t >= CCH) return;
    int cls = (int)clsbase[0]; float base = clsbase[1];
    float s = 0.f;
    for (int q = 0; q < 64; ++q) s += logit_part[q * CCH + t];
    alpha[t] = (base - (s + b3[cls])) / base;
}

__global__ void k_resize2(const float* __restrict__ alpha, const float* __restrict__ act,
                          float* __restrict__ out, int* __restrict__ minmax) {
    __shared__ float sA[CCH];
    __shared__ float sW[196];
    int t = threadIdx.x;
    for (int i = t; i < CCH; i += 256) sA[i] = alpha[i];
    __syncthreads();
    if (t < 196) {
        float s = 0.f;
        for (int c = 0; c < CCH; ++c) s = fmaf(sA[c], act[c * 196 + t], s);
        sW[t] = s;
    }
    __syncthreads();
    int pix = blockIdx.x * 256 + t;
    int y = pix / OW, x = pix % OW;
    float uy = (y + 0.5f) * 0.0625f - 0.5f;
    float ux = (x + 0.5f) * 0.0625f - 0.5f;
    float y0f = floorf(uy), x0f = floorf(ux);
    float fy = uy - y0f, fx = ux - x0f;
    int y0 = (int)y0f, x0 = (int)x0f;
    int y0c = min(max(y0, 0), 13), y1c = min(max(y0 + 1, 0), 13);
    int x0c = min(max(x0, 0), 13), x1c = min(max(x0 + 1, 0), 13);
    float v00 = sW[y0c * 14 + x0c], v01 = sW[y0c * 14 + x1c];
    float v10 = sW[y1c * 14 + x0c], v11 = sW[y1c * 14 + x1c];
    float v0 = v00 + (v01 - v00) * fx;
    float v1 = v10 + (v11 - v10) * fx;
    float v = v0 + (v1 - v0) * fy;
    float f = fmaxf(v, 0.f);
    out[pix] = f;
    __shared__ float rmn[256], rmx[256];
    rmn[t] = f; rmx[t] = f; __syncthreads();
    for (int o = 128; o > 0; o >>= 1) {
        if (t < o) { rmn[t] = fminf(rmn[t], rmn[t + o]); rmx[t] = fmaxf(rmx[t], rmx[t + o]); }
        __syncthreads();
    }
    if (t == 0) {
        atomicMin(&minmax[0], __float_as_int(rmn[0]));
        atomicMax(&minmax[1], __float_as_int(rmx[0]));
    }
}

__global__ void k_norm(float* __restrict__ out, const int* __restrict__ minmax) {
    float mn = __int_as_float(minmax[0]);
    float mx = __int_as_float(minmax[1]);
    int pix = blockIdx.x * 256 + threadIdx.x;
    if (mx != mn) out[pix] = (out[pix] - mn) / (mx - mn);
}

extern "C" void kernel_launch(void* const* d_in, const int* in_sizes, int n_in,
                              void* d_out, int out_size, void* d_ws, size_t ws_size,
                              hipStream_t stream) {
    const float* act = (const float*)d_in[0];
    const float* W1  = (const float*)d_in[1];
    const float* b1  = (const float*)d_in[2];
    const float* W2  = (const float*)d_in[3];
    const float* b2  = (const float*)d_in[4];
    const float* W3  = (const float*)d_in[5];
    const float* b3  = (const float*)d_in[6];
    float* out = (float*)d_out;
    float* ws = (float*)d_ws;
    const bool fast = (ws_size >= WS_NEED_BYTES);

    k_maxpool<<<98, 256, 0, stream>>>(act, ws);
    k_phi7<<<4096, 256, 0, stream>>>(W1, ws + WS_MP, b1, ws + WS_DT,
                                     ws + WS_H1PRE, ws + WS_H1);
    if (fast) {
        k_abuild<<<dim3(64, 8), 256, 0, stream>>>(ws + WS_DT, ws + WS_H1PRE,
                                                  (unsigned short*)(ws + WS_A));
        k_mfma_v6<<<512, 512, 0, stream>>>(
            (const unsigned short*)(ws + WS_A), W2, ws + WS_H1,
            (unsigned short*)(ws + WS_PARTB), ws + WS_H2PART);
        k_tail1<<<NCLS, 256, 0, stream>>>(ws + WS_H2PART, b2, W3, b3, ws, out,
                                          (int*)(ws + WS_CNT));
        k_tail2<<<CCH, 256, 0, stream>>>((const unsigned short*)(ws + WS_PARTB), b2,
                                         W3, b3, act, ws, out,
                                         (int*)(ws + WS_CNT) + 1);
    } else {
        k_gemv4096<true><<<4096, 256, 0, stream>>>(W2, ws + WS_H1, b2, ws + WS_H2);
        k_gemv4096<false><<<1000, 256, 0, stream>>>(W3, ws + WS_H2, b3, ws + WS_LOGITS);
        k_argmax<<<1, 256, 0, stream>>>(ws + WS_LOGITS, ws + WS_CLSBASE, out + 50176);
        k_gemm_abl<<<dim3(8, 64), 256, 0, stream>>>(ws + WS_DT, ws + WS_H1PRE, W2, b2,
                                                    W3, ws + WS_CLSBASE, ws + WS_LOGPART);
        k_alpha_fb<<<2, 256, 0, stream>>>(ws + WS_LOGPART, b3, ws + WS_CLSBASE,
                                          ws + WS_ALPHA);
        k_resize2<<<196, 256, 0, stream>>>(ws + WS_ALPHA, act, out, (int*)(ws + WS_MINMAX));
        k_norm<<<196, 256, 0, stream>>>(out, (const int*)(ws + WS_MINMAX));
    }
}

// Round 11
// 208.707 us; speedup vs baseline: 2.0218x; 2.0218x over previous
//
#include <hip/hip_runtime.h>
#include <math.h>

#define CCH 512
#define F1 25088      // 512*49
#define FC 4096
#define NCLS 1000
#define OW 224
#define KSPLIT 8
#define KSL 512       // FC/KSPLIT
#define PSTRIDE (CCH*FC)   // one bf16 partial plane (ushort elems)

// ws float offsets
#define WS_DT 0                          // [4096][512] f32
#define WS_MP (WS_DT + FC*CCH)           // 25088
#define WS_H1PRE (WS_MP + F1)            // 4096
#define WS_H1 (WS_H1PRE + FC)            // 4096
#define WS_H2 (WS_H1 + FC)               // 4096
#define WS_H2PART (WS_H2 + FC)           // [8][4096]
#define WS_LOGITS (WS_H2PART + 8*FC)     // 1000
#define WS_CLSBASE (WS_LOGITS + NCLS)    // 2
#define WS_ALPHA (WS_CLSBASE + 2)        // 512
#define WS_MINMAX (WS_ALPHA + CCH)       // 2 ints
#define WS_LOGPART (WS_MINMAX + 2)       // [64][512] (fallback)
#define WS_A (WS_LOGPART + 64*CCH)       // bf16 [512][4096]
#define WS_PARTB (WS_A + CCH*FC/2)       // bf16 [8][512][4096]
#define WS_END (WS_PARTB + KSPLIT*CCH*FC/2)
#define WS_NEED_BYTES ((size_t)WS_END * 4)

typedef __attribute__((ext_vector_type(8))) short bfrag;
typedef __attribute__((ext_vector_type(4))) float f32x4;

static __device__ __forceinline__ unsigned short f2bf(float x) {
    unsigned u = __float_as_uint(x);
    unsigned r = 0x7FFFu + ((u >> 16) & 1u);
    return (unsigned short)((u + r) >> 16);
}

#define GLD16(g, l) __builtin_amdgcn_global_load_lds( \
    (const __attribute__((address_space(1))) void*)(g), \
    (__attribute__((address_space(3))) void*)(l), 16, 0, 0)

// -------- maxpool 2x2 (+ init minmax) --------
__global__ void k_maxpool(const float* __restrict__ act, float* __restrict__ ws) {
    int t = threadIdx.x;
    if (blockIdx.x == 0) {
        if (t == 0) ((int*)(ws + WS_MINMAX))[0] = 0x7F800000;
        if (t == 1) ((int*)(ws + WS_MINMAX))[1] = 0;
    }
    int idx = blockIdx.x * 256 + t;
    if (idx >= CCH * 49) return;
    int c = idx / 49, r = idx % 49, y = r / 7, x = r % 7;
    const float* a = act + c * 196 + (2 * y) * 14 + 2 * x;
    float m = fmaxf(fmaxf(a[0], a[1]), fmaxf(a[14], a[15]));
    ws[WS_MP + idx] = m;
}

// -------- layer-1 partials + fused h1, batched loads --------
__global__ __launch_bounds__(256) void k_phi7(const float* __restrict__ W1,
                                              const float* __restrict__ mp,
                                              const float* __restrict__ b1,
                                              float* __restrict__ Dt,
                                              float* __restrict__ h1pre,
                                              float* __restrict__ h1) {
    __shared__ float buf[12544];
    __shared__ float red[256];
    int j = blockIdx.x, t = threadIdx.x;
    const float4* wrow = (const float4*)(W1 + (size_t)j * F1);
    const float4* mrow = (const float4*)mp;
    float sh = 0.f;
    #pragma unroll
    for (int h = 0; h < 2; ++h) {
        const float4* src = wrow + h * 3136;
        const float4* msc = mrow + h * 3136;
        __syncthreads();
        #pragma unroll
        for (int b = 0; b < 2; ++b) {
            float4 w[6], m[6];
            #pragma unroll
            for (int e = 0; e < 6; ++e) {
                int n = t + 256 * (b * 6 + e);
                w[e] = src[n]; m[e] = msc[n];
            }
            #pragma unroll
            for (int e = 0; e < 6; ++e) {
                int n = t + 256 * (b * 6 + e);
                float4 p;
                p.x = w[e].x * m[e].x; p.y = w[e].y * m[e].y;
                p.z = w[e].z * m[e].z; p.w = w[e].w * m[e].w;
                *(float4*)&buf[n * 4] = p;
            }
        }
        if (t < 64) {
            int n = 3072 + t;
            float4 w = src[n], m = msc[n];
            float4 p;
            p.x = w.x * m.x; p.y = w.y * m.y; p.z = w.z * m.z; p.w = w.w * m.w;
            *(float4*)&buf[n * 4] = p;
        }
        __syncthreads();
        const float* bb = buf + t * 49;
        float s = 0.f;
        #pragma unroll
        for (int k = 0; k < 49; ++k) s += bb[k];
        Dt[(size_t)j * CCH + h * 256 + t] = s;
        sh += s;
    }
    red[t] = sh;
    __syncthreads();
    if (t < 128) red[t] += red[t + 128];
    __syncthreads();
    if (t < 64) {
        float v = red[t] + red[t + 64];
        for (int off = 32; off > 0; off >>= 1) v += __shfl_down(v, off, 64);
        if (t == 0) { float hv = b1[j] + v; h1pre[j] = hv; h1[j] = fmaxf(hv, 0.f); }
    }
}

// -------- K=4096 GEMV (vectorized) --------
template <bool RELU>
__global__ void k_gemv4096(const float* __restrict__ M, const float* __restrict__ v,
                           const float* __restrict__ bias, float* __restrict__ out) {
    int j = blockIdx.x, t = threadIdx.x;
    const float4* row = (const float4*)(M + (size_t)j * FC);
    const float4* vv = (const float4*)v;
    float s = 0.f;
    #pragma unroll
    for (int q = 0; q < 4; ++q) {
        int n = q * 256 + t;
        float4 w = row[n], x = vv[n];
        s += w.x * x.x + w.y * x.y + w.z * x.z + w.w * x.w;
    }
    __shared__ float red[256];
    red[t] = s; __syncthreads();
    if (t < 128) red[t] += red[t + 128]; __syncthreads();
    if (t < 64)  red[t] += red[t + 64];  __syncthreads();
    if (t < 64) {
        float x = red[t];
        for (int off = 32; off > 0; off >>= 1) x += __shfl_down(x, off, 64);
        if (t == 0) { float r2 = bias[j] + x; out[j] = RELU ? fmaxf(r2, 0.f) : r2; }
    }
}

// -------- argmax over logits --------
__global__ void k_argmax(const float* __restrict__ logits, float* __restrict__ clsbase,
                         float* __restrict__ dout_cls) {
    int t = threadIdx.x;
    float best = -INFINITY; int bi = NCLS;
    for (int n = t; n < NCLS; n += 256) {
        float v = logits[n];
        if (v > best || (v == best && n < bi)) { best = v; bi = n; }
    }
    __shared__ float bv[256]; __shared__ int bidx[256];
    bv[t] = best; bidx[t] = bi; __syncthreads();
    for (int o = 128; o > 0; o >>= 1) {
        if (t < o) {
            float v2 = bv[t + o]; int i2 = bidx[t + o];
            if (v2 > bv[t] || (v2 == bv[t] && i2 < bidx[t])) { bv[t] = v2; bidx[t] = i2; }
        }
        __syncthreads();
    }
    if (t == 0) { clsbase[0] = (float)bidx[0]; clsbase[1] = bv[0]; *dout_cls = (float)bidx[0]; }
}

// -------- A[i][k] = relu(h1pre[k] - Dt[k][i]) in bf16, [512][4096] --------
__global__ __launch_bounds__(256) void k_abuild(const float* __restrict__ Dt,
                                                const float* __restrict__ h1pre,
                                                unsigned short* __restrict__ A) {
    __shared__ unsigned short tile[64][72];
    int kt = blockIdx.x, it = blockIdx.y, t = threadIdx.x;
    int k0 = kt * 64, i0 = it * 64;
    #pragma unroll
    for (int q = 0; q < 16; ++q) {
        int kk = q * 4 + (t >> 6);
        int ii = t & 63;
        float v = fmaxf(h1pre[k0 + kk] - Dt[(size_t)(k0 + kk) * CCH + i0 + ii], 0.f);
        tile[kk][ii] = f2bf(v);
    }
    __syncthreads();
    #pragma unroll
    for (int q = 0; q < 4; ++q) {
        int c = q * 256 + t;
        int ii = c >> 4, kc = c & 15;
        ushort4 v;
        v.x = tile[kc * 4 + 0][ii]; v.y = tile[kc * 4 + 1][ii];
        v.z = tile[kc * 4 + 2][ii]; v.w = tile[kc * 4 + 3][ii];
        *(ushort4*)&A[(size_t)(i0 + ii) * FC + k0 + kc * 4] = v;
    }
}

// -------- ablation GEMM v7: m97 geometry (128x128 tile, BK=64, 4 blocks/CU) --------
// grid 1024: ks=bid&7 (->XCD, A k-slice L2-resident), mi=(bid>>3)&3, nj=bid>>5.
// partb[ks][i][j] = sum_{k in slice} A[i][k]*W2bf[j][k]   (bf16)
// h2part[ks][j]   = sum_{k in slice} W2f32[j][k]*h1[k]    (mi==0 blocks)
__global__ __launch_bounds__(256) void k_mfma_v7(
    const unsigned short* __restrict__ A, const float* __restrict__ W2,
    const float* __restrict__ h1, unsigned short* __restrict__ partb,
    float* __restrict__ h2part) {
    __shared__ char As[16384];     // 128 rows x 8 chunks x 16B (BK=64 bf16)
    __shared__ char Bs[16384];
    __shared__ float h1s[KSL];     // 2KB
    int bid = blockIdx.x;
    int ks = bid & 7;
    int mi = (bid >> 3) & 3;
    int nj = bid >> 5;             // 0..31
    int t = threadIdx.x;
    int wid = t >> 6, lane = t & 63, lr = lane & 15, lh = lane >> 4;
    int wm = wid >> 1, wn = wid & 1;   // wave quadrant of the 128x128 C tile
    int i0 = mi * 128, j0 = nj * 128;
    int kb = ks * KSL;

    {   // stage h1 slice (512 floats)
        float2 v = *(const float2*)(h1 + kb + t * 2);
        *(float2*)&h1s[t * 2] = v;
    }

    bool doh = (mi == 0);
    float hacc[4] = {0.f, 0.f, 0.f, 0.f};
    f32x4 acc[4][4];
    #pragma unroll
    for (int f = 0; f < 4; ++f)
        #pragma unroll
        for (int n = 0; n < 4; ++n) acc[f][n] = (f32x4){0.f, 0.f, 0.f, 0.f};

    for (int kst = 0; kst < KSL; kst += 64) {
        __syncthreads();   // prev compute done reading LDS (publishes h1s iter 0)
        // stage A: 1024 chunks of 16B, pre-swizzled global source, linear LDS dest
        #pragma unroll
        for (int r = 0; r < 4; ++r) {
            int c = t + 256 * r;
            int row = c >> 3, ch = c & 7;
            GLD16(A + (size_t)(i0 + row) * FC + kb + kst + ((ch ^ (row & 7)) * 8),
                  As + (size_t)c * 16);
        }
        // stage B: 4 chunks/thread, fp32 load (pre-swizzled k), cvt, linear ds_write
        #pragma unroll
        for (int r = 0; r < 4; ++r) {
            int c = t + 256 * r;
            int row = c >> 3, ch = c & 7;
            int ko = (ch ^ (row & 7)) * 8;
            const float* wp = W2 + (size_t)(j0 + row) * FC + kb + kst + ko;
            float4 wa = ((const float4*)wp)[0];
            float4 wb = ((const float4*)wp)[1];
            if (doh) {
                hacc[r] += wa.x * h1s[kst + ko + 0] + wa.y * h1s[kst + ko + 1]
                         + wa.z * h1s[kst + ko + 2] + wa.w * h1s[kst + ko + 3]
                         + wb.x * h1s[kst + ko + 4] + wb.y * h1s[kst + ko + 5]
                         + wb.z * h1s[kst + ko + 6] + wb.w * h1s[kst + ko + 7];
            }
            union { bfrag v; unsigned short u[8]; } pk;
            pk.u[0] = f2bf(wa.x); pk.u[1] = f2bf(wa.y);
            pk.u[2] = f2bf(wa.z); pk.u[3] = f2bf(wa.w);
            pk.u[4] = f2bf(wb.x); pk.u[5] = f2bf(wb.y);
            pk.u[6] = f2bf(wb.z); pk.u[7] = f2bf(wb.w);
            *(bfrag*)(Bs + (size_t)c * 16) = pk.v;
        }
        __syncthreads();   // drains vmcnt (gld_lds) + lgkm (ds_write)
        // compute: 32 MFMA per wave (2 kf x 4 f x 4 n)
        #pragma unroll
        for (int kf = 0; kf < 2; ++kf) {
            bfrag bfr[4];
            #pragma unroll
            for (int n = 0; n < 4; ++n) {
                int br = wn * 64 + n * 16 + lr;
                bfr[n] = *(const bfrag*)(Bs + ((size_t)(br * 8) + ((kf * 4 + lh) ^ (br & 7))) * 16);
            }
            #pragma unroll
            for (int f = 0; f < 4; ++f) {
                int ar = wm * 64 + f * 16 + lr;
                bfrag av = *(const bfrag*)(As + ((size_t)(ar * 8) + ((kf * 4 + lh) ^ (ar & 7))) * 16);
                #pragma unroll
                for (int n = 0; n < 4; ++n)
                    acc[f][n] = __builtin_amdgcn_mfma_f32_16x16x32_bf16(av, bfr[n], acc[f][n], 0, 0, 0);
            }
        }
    }

    // h2 partials: per r, 8 consecutive threads share W2 row (r*32 + t>>3)
    if (doh) {
        #pragma unroll
        for (int r = 0; r < 4; ++r) {
            float v = hacc[r];
            v += __shfl_down(v, 4, 8);
            v += __shfl_down(v, 2, 8);
            v += __shfl_down(v, 1, 8);
            if ((t & 7) == 0) h2part[ks * FC + j0 + r * 32 + (t >> 3)] = v;
        }
    }
    // epilogue: bf16 partials
    unsigned short* pb = partb + (size_t)ks * PSTRIDE;
    #pragma unroll
    for (int f = 0; f < 4; ++f) {
        int row0 = i0 + wm * 64 + f * 16 + lh * 4;
        #pragma unroll
        for (int rr = 0; rr < 4; ++rr)
            #pragma unroll
            for (int n = 0; n < 4; ++n)
                pb[(size_t)(row0 + rr) * FC + j0 + wn * 64 + n * 16 + lr] = f2bf(acc[f][n][rr]);
    }
}

// -------- h2 = relu(b2 + sum of 8 k-partials) --------
__global__ void k_h2sum(const float* __restrict__ h2part, const float* __restrict__ b2,
                        float* __restrict__ h2) {
    int j = blockIdx.x * 256 + threadIdx.x;
    if (j < FC) {
        float v = b2[j];
        #pragma unroll
        for (int p = 0; p < KSPLIT; ++p) v += h2part[p * FC + j];
        h2[j] = fmaxf(v, 0.f);
    }
}

// -------- per-ablation class logit from bf16 k-partials + alpha --------
__global__ __launch_bounds__(256) void k_alpha_b(
    const unsigned short* __restrict__ partb, const float* __restrict__ b2,
    const float* __restrict__ W3, const float* __restrict__ b3,
    const float* __restrict__ clsbase, float* __restrict__ alpha) {
    int i = blockIdx.x, t = threadIdx.x;
    int cls = (int)clsbase[0]; float base = clsbase[1];
    const float* w3r = W3 + (size_t)cls * FC;
    float s = 0.f;
    #pragma unroll
    for (int q = 0; q < 2; ++q) {
        int jj = (q * 256 + t) * 8;
        float acc8[8];
        #pragma unroll
        for (int e = 0; e < 8; ++e) acc8[e] = b2[jj + e];
        #pragma unroll
        for (int p = 0; p < KSPLIT; ++p) {
            uint4 pv = *(const uint4*)(partb + (size_t)p * PSTRIDE + (size_t)i * FC + jj);
            #pragma unroll
            for (int e = 0; e < 4; ++e) {
                unsigned a = ((const unsigned*)&pv)[e];
                acc8[e * 2]     += __uint_as_float(a << 16);
                acc8[e * 2 + 1] += __uint_as_float(a & 0xFFFF0000u);
            }
        }
        #pragma unroll
        for (int e = 0; e < 8; ++e) s += fmaxf(acc8[e], 0.f) * w3r[jj + e];
    }
    __shared__ float red[256];
    red[t] = s; __syncthreads();
    if (t < 128) red[t] += red[t + 128]; __syncthreads();
    if (t < 64)  red[t] += red[t + 64];  __syncthreads();
    if (t < 64) {
        float x = red[t];
        for (int off = 32; off > 0; off >>= 1) x += __shfl_down(x, off, 64);
        if (t == 0) alpha[i] = (base - (x + b3[cls])) / base;
    }
}

// ======== fallback fp32 path (ws too small) ========
__global__ __launch_bounds__(256) void k_gemm_abl(
    const float* __restrict__ Dt, const float* __restrict__ h1pre,
    const float* __restrict__ W2, const float* __restrict__ b2,
    const float* __restrict__ W3, const float* __restrict__ clsbase,
    float* __restrict__ logit_part) {
    int mi = blockIdx.x, nj = blockIdx.y, t = threadIdx.x;
    int tx = t & 15, ty = t >> 4;
    int i0 = mi * 64, j0 = nj * 64;
    __shared__ float As2[16][64];
    __shared__ float Bs2[16][65];
    float acc[4][4] = {};
    for (int k0 = 0; k0 < FC; k0 += 16) {
        #pragma unroll
        for (int r = 0; r < 4; ++r) {
            int e = t + 256 * r; int kk = e >> 6, ii = e & 63;
            As2[kk][ii] = fmaxf(h1pre[k0 + kk] - Dt[(size_t)(k0 + kk) * CCH + i0 + ii], 0.f);
        }
        {
            int jj = t >> 2, kks = (t & 3) * 4;
            const float4 wv = *(const float4*)(W2 + (size_t)(j0 + jj) * FC + k0 + kks);
            Bs2[kks + 0][jj] = wv.x; Bs2[kks + 1][jj] = wv.y;
            Bs2[kks + 2][jj] = wv.z; Bs2[kks + 3][jj] = wv.w;
        }
        __syncthreads();
        #pragma unroll
        for (int kk = 0; kk < 16; ++kk) {
            float4 a4 = *(const float4*)&As2[kk][tx * 4];
            float av[4] = {a4.x, a4.y, a4.z, a4.w};
            float bv[4] = {Bs2[kk][ty * 4 + 0], Bs2[kk][ty * 4 + 1],
                           Bs2[kk][ty * 4 + 2], Bs2[kk][ty * 4 + 3]};
            #pragma unroll
            for (int a = 0; a < 4; ++a)
                #pragma unroll
                for (int bb = 0; bb < 4; ++bb)
                    acc[a][bb] = fmaf(av[a], bv[bb], acc[a][bb]);
        }
        __syncthreads();
    }
    int cls = (int)clsbase[0];
    const float* w3r = W3 + (size_t)cls * FC;
    float prt[4] = {0.f, 0.f, 0.f, 0.f};
    #pragma unroll
    for (int bb = 0; bb < 4; ++bb) {
        int j2 = j0 + ty * 4 + bb;
        float b2v = b2[j2], w3 = w3r[j2];
        #pragma unroll
        for (int a = 0; a < 4; ++a) prt[a] = fmaf(fmaxf(acc[a][bb] + b2v, 0.f), w3, prt[a]);
    }
    __shared__ float red2[16][68];
    #pragma unroll
    for (int a = 0; a < 4; ++a) red2[ty][tx * 4 + a] = prt[a];
    __syncthreads();
    if (t < 64) {
        float s = 0.f;
        #pragma unroll
        for (int q = 0; q < 16; ++q) s += red2[q][t];
        logit_part[nj * CCH + i0 + t] = s;
    }
}

__global__ void k_alpha_fb(const float* __restrict__ logit_part, const float* __restrict__ b3,
                           const float* __restrict__ clsbase, float* __restrict__ alpha) {
    int t = blockIdx.x * 256 + threadIdx.x;
    if (t >= CCH) return;
    int cls = (int)clsbase[0]; float base = clsbase[1];
    float s = 0.f;
    for (int q = 0; q < 64; ++q) s += logit_part[q * CCH + t];
    alpha[t] = (base - (s + b3[cls])) / base;
}

// -------- fused weighted-map + bilinear 14->224 + relu + min/max --------
__global__ void k_resize2(const float* __restrict__ alpha, const float* __restrict__ act,
                          float* __restrict__ out, int* __restrict__ minmax) {
    __shared__ float sA[CCH];
    __shared__ float sW[196];
    int t = threadIdx.x;
    for (int i = t; i < CCH; i += 256) sA[i] = alpha[i];
    __syncthreads();
    if (t < 196) {
        float s = 0.f;
        for (int c = 0; c < CCH; ++c) s = fmaf(sA[c], act[c * 196 + t], s);
        sW[t] = s;
    }
    __syncthreads();
    int pix = blockIdx.x * 256 + t;
    int y = pix / OW, x = pix % OW;
    float uy = (y + 0.5f) * 0.0625f - 0.5f;
    float ux = (x + 0.5f) * 0.0625f - 0.5f;
    float y0f = floorf(uy), x0f = floorf(ux);
    float fy = uy - y0f, fx = ux - x0f;
    int y0 = (int)y0f, x0 = (int)x0f;
    int y0c = min(max(y0, 0), 13), y1c = min(max(y0 + 1, 0), 13);
    int x0c = min(max(x0, 0), 13), x1c = min(max(x0 + 1, 0), 13);
    float v00 = sW[y0c * 14 + x0c], v01 = sW[y0c * 14 + x1c];
    float v10 = sW[y1c * 14 + x0c], v11 = sW[y1c * 14 + x1c];
    float v0 = v00 + (v01 - v00) * fx;
    float v1 = v10 + (v11 - v10) * fx;
    float v = v0 + (v1 - v0) * fy;
    float f = fmaxf(v, 0.f);
    out[pix] = f;
    __shared__ float rmn[256], rmx[256];
    rmn[t] = f; rmx[t] = f; __syncthreads();
    for (int o = 128; o > 0; o >>= 1) {
        if (t < o) { rmn[t] = fminf(rmn[t], rmn[t + o]); rmx[t] = fmaxf(rmx[t], rmx[t + o]); }
        __syncthreads();
    }
    if (t == 0) {
        atomicMin(&minmax[0], __float_as_int(rmn[0]));
        atomicMax(&minmax[1], __float_as_int(rmx[0]));
    }
}

__global__ void k_norm(float* __restrict__ out, const int* __restrict__ minmax) {
    float mn = __int_as_float(minmax[0]);
    float mx = __int_as_float(minmax[1]);
    int pix = blockIdx.x * 256 + threadIdx.x;
    if (mx != mn) out[pix] = (out[pix] - mn) / (mx - mn);
}

extern "C" void kernel_launch(void* const* d_in, const int* in_sizes, int n_in,
                              void* d_out, int out_size, void* d_ws, size_t ws_size,
                              hipStream_t stream) {
    const float* act = (const float*)d_in[0];
    const float* W1  = (const float*)d_in[1];
    const float* b1  = (const float*)d_in[2];
    const float* W2  = (const float*)d_in[3];
    const float* b2  = (const float*)d_in[4];
    const float* W3  = (const float*)d_in[5];
    const float* b3  = (const float*)d_in[6];
    float* out = (float*)d_out;
    float* ws = (float*)d_ws;
    const bool fast = (ws_size >= WS_NEED_BYTES);

    k_maxpool<<<98, 256, 0, stream>>>(act, ws);
    k_phi7<<<4096, 256, 0, stream>>>(W1, ws + WS_MP, b1, ws + WS_DT,
                                     ws + WS_H1PRE, ws + WS_H1);
    if (fast) {
        k_abuild<<<dim3(64, 8), 256, 0, stream>>>(ws + WS_DT, ws + WS_H1PRE,
                                                  (unsigned short*)(ws + WS_A));
        k_mfma_v7<<<1024, 256, 0, stream>>>(
            (const unsigned short*)(ws + WS_A), W2, ws + WS_H1,
            (unsigned short*)(ws + WS_PARTB), ws + WS_H2PART);
        k_h2sum<<<16, 256, 0, stream>>>(ws + WS_H2PART, b2, ws + WS_H2);
        k_gemv4096<false><<<1000, 256, 0, stream>>>(W3, ws + WS_H2, b3, ws + WS_LOGITS);
        k_argmax<<<1, 256, 0, stream>>>(ws + WS_LOGITS, ws + WS_CLSBASE, out + 50176);
        k_alpha_b<<<CCH, 256, 0, stream>>>((const unsigned short*)(ws + WS_PARTB), b2,
                                           W3, b3, ws + WS_CLSBASE, ws + WS_ALPHA);
    } else {
        k_gemv4096<true><<<4096, 256, 0, stream>>>(W2, ws + WS_H1, b2, ws + WS_H2);
        k_gemv4096<false><<<1000, 256, 0, stream>>>(W3, ws + WS_H2, b3, ws + WS_LOGITS);
        k_argmax<<<1, 256, 0, stream>>>(ws + WS_LOGITS, ws + WS_CLSBASE, out + 50176);
        k_gemm_abl<<<dim3(8, 64), 256, 0, stream>>>(ws + WS_DT, ws + WS_H1PRE, W2, b2,
                                                    W3, ws + WS_CLSBASE, ws + WS_LOGPART);
        k_alpha_fb<<<2, 256, 0, stream>>>(ws + WS_LOGPART, b3, ws + WS_CLSBASE,
                                          ws + WS_ALPHA);
    }
    k_resize2<<<196, 256, 0, stream>>>(ws + WS_ALPHA, act, out, (int*)(ws + WS_MINMAX));
    k_norm<<<196, 256, 0, stream>>>(out, (const int*)(ws + WS_MINMAX));
}

// Round 12
// 200.289 us; speedup vs baseline: 2.1068x; 1.0420x over previous
//
#include <hip/hip_runtime.h>
#include <math.h>

#define CCH 512
#define F1 25088      // 512*49
#define FC 4096
#define NCLS 1000
#define OW 224
#define KSPLIT 4
#define KSL 1024      // FC/KSPLIT
#define PSTRIDE (CCH*FC)   // one bf16 partial plane (ushort elems)

// ws float offsets
#define WS_DT 0                          // [4096][512] f32
#define WS_MP (WS_DT + FC*CCH)           // 25088
#define WS_H1PRE (WS_MP + F1)            // 4096
#define WS_H1 (WS_H1PRE + FC)            // 4096
#define WS_H2 (WS_H1 + FC)               // 4096 (fallback)
#define WS_H2PART (WS_H2 + FC)           // [KSPLIT][4096]
#define WS_LOGITS (WS_H2PART + KSPLIT*FC)
#define WS_CLSBASE (WS_LOGITS + NCLS)    // 2
#define WS_ALPHA (WS_CLSBASE + 2)        // 512
#define WS_MINMAX (WS_ALPHA + CCH)       // 2 ints
#define WS_LOGPART (WS_MINMAX + 2)       // [64][512] (fallback)
#define WS_A (WS_LOGPART + 64*CCH)       // bf16 [512][4096]
#define WS_PARTB (WS_A + CCH*FC/2)       // bf16 [KSPLIT][512][4096]
#define WS_END (WS_PARTB + KSPLIT*CCH*FC/2)
#define WS_NEED_BYTES ((size_t)WS_END * 4)

typedef __attribute__((ext_vector_type(8))) short bfrag;
typedef __attribute__((ext_vector_type(4))) float f32x4;

static __device__ __forceinline__ unsigned short f2bf(float x) {
    unsigned u = __float_as_uint(x);
    unsigned r = 0x7FFFu + ((u >> 16) & 1u);
    return (unsigned short)((u + r) >> 16);
}

#define GLD16(g, l) __builtin_amdgcn_global_load_lds( \
    (const __attribute__((address_space(1))) void*)(g), \
    (__attribute__((address_space(3))) void*)(l), 16, 0, 0)

// -------- maxpool 2x2 (+ init minmax) --------
__global__ void k_maxpool(const float* __restrict__ act, float* __restrict__ ws) {
    int t = threadIdx.x;
    if (blockIdx.x == 0) {
        if (t == 0) ((int*)(ws + WS_MINMAX))[0] = 0x7F800000;
        if (t == 1) ((int*)(ws + WS_MINMAX))[1] = 0;
    }
    int idx = blockIdx.x * 256 + t;
    if (idx >= CCH * 49) return;
    int c = idx / 49, r = idx % 49, y = r / 7, x = r % 7;
    const float* a = act + c * 196 + (2 * y) * 14 + 2 * x;
    float m = fmaxf(fmaxf(a[0], a[1]), fmaxf(a[14], a[15]));
    ws[WS_MP + idx] = m;
}

// -------- layer-1 partials + fused h1: quarter double-buffer, T14 split --------
// Per quarter: issue loads(q+1) -> sum(q) under load latency -> write-late -> barrier.
__global__ __launch_bounds__(256) void k_phi8(const float* __restrict__ W1,
                                              const float* __restrict__ mp,
                                              const float* __restrict__ b1,
                                              float* __restrict__ Dt,
                                              float* __restrict__ h1pre,
                                              float* __restrict__ h1) {
    __shared__ float buf[2][6272];   // 2 x 24.5KB
    __shared__ float red[128];
    int j = blockIdx.x, t = threadIdx.x;
    const float4* wrow = (const float4*)(W1 + (size_t)j * F1);
    const float4* mrow = (const float4*)mp;

    {   // stage quarter 0 into buf[0]
        float4 w[6], m[6], wt, mt;
        #pragma unroll
        for (int e = 0; e < 6; ++e) { int n = t + 256 * e; w[e] = wrow[n]; m[e] = mrow[n]; }
        if (t < 32) { int n = 1536 + t; wt = wrow[n]; mt = mrow[n]; }
        #pragma unroll
        for (int e = 0; e < 6; ++e) {
            int n = t + 256 * e;
            float4 p;
            p.x = w[e].x * m[e].x; p.y = w[e].y * m[e].y;
            p.z = w[e].z * m[e].z; p.w = w[e].w * m[e].w;
            *(float4*)&buf[0][n * 4] = p;
        }
        if (t < 32) {
            int n = 1536 + t;
            float4 p;
            p.x = wt.x * mt.x; p.y = wt.y * mt.y; p.z = wt.z * mt.z; p.w = wt.w * mt.w;
            *(float4*)&buf[0][n * 4] = p;
        }
    }
    __syncthreads();

    float hacc = 0.f;
    #pragma unroll
    for (int q = 0; q < 4; ++q) {
        int cb = q & 1;
        float4 w[6], m[6], wt, mt;
        if (q < 3) {   // issue-early: loads for quarter q+1
            const float4* src = wrow + (q + 1) * 1568;
            const float4* msc = mrow + (q + 1) * 1568;
            #pragma unroll
            for (int e = 0; e < 6; ++e) { int n = t + 256 * e; w[e] = src[n]; m[e] = msc[n]; }
            if (t < 32) { int n = 1536 + t; wt = src[n]; mt = msc[n]; }
        }
        // sum current quarter under the load latency (threads 0..127, one channel each)
        if (t < 128) {
            const float* bb = buf[cb] + t * 49;   // stride 49: 2 lanes/bank (free)
            float s = 0.f;
            #pragma unroll
            for (int k = 0; k < 49; ++k) s += bb[k];
            Dt[(size_t)j * CCH + q * 128 + t] = s;
            hacc += s;
        }
        if (q < 3) {   // write-late into the other buffer
            float* dst = buf[cb ^ 1];
            #pragma unroll
            for (int e = 0; e < 6; ++e) {
                int n = t + 256 * e;
                float4 p;
                p.x = w[e].x * m[e].x; p.y = w[e].y * m[e].y;
                p.z = w[e].z * m[e].z; p.w = w[e].w * m[e].w;
                *(float4*)&dst[n * 4] = p;
            }
            if (t < 32) {
                int n = 1536 + t;
                float4 p;
                p.x = wt.x * mt.x; p.y = wt.y * mt.y; p.z = wt.z * mt.z; p.w = wt.w * mt.w;
                *(float4*)&dst[n * 4] = p;
            }
        }
        __syncthreads();
    }
    if (t < 128) red[t] = hacc;
    __syncthreads();
    if (t < 64) {
        float v = red[t] + red[t + 64];
        for (int off = 32; off > 0; off >>= 1) v += __shfl_down(v, off, 64);
        if (t == 0) { float hv = b1[j] + v; h1pre[j] = hv; h1[j] = fmaxf(hv, 0.f); }
    }
}

// -------- A[i][k] = relu(h1pre[k] - Dt[k][i]) in bf16, [512][4096] --------
__global__ __launch_bounds__(256) void k_abuild(const float* __restrict__ Dt,
                                                const float* __restrict__ h1pre,
                                                unsigned short* __restrict__ A) {
    __shared__ unsigned short tile[64][72];
    int kt = blockIdx.x, it = blockIdx.y, t = threadIdx.x;
    int k0 = kt * 64, i0 = it * 64;
    #pragma unroll
    for (int q = 0; q < 16; ++q) {
        int kk = q * 4 + (t >> 6);
        int ii = t & 63;
        float v = fmaxf(h1pre[k0 + kk] - Dt[(size_t)(k0 + kk) * CCH + i0 + ii], 0.f);
        tile[kk][ii] = f2bf(v);
    }
    __syncthreads();
    #pragma unroll
    for (int q = 0; q < 4; ++q) {
        int c = q * 256 + t;
        int ii = c >> 4, kc = c & 15;
        ushort4 v;
        v.x = tile[kc * 4 + 0][ii]; v.y = tile[kc * 4 + 1][ii];
        v.z = tile[kc * 4 + 2][ii]; v.w = tile[kc * 4 + 3][ii];
        *(ushort4*)&A[(size_t)(i0 + ii) * FC + k0 + kc * 4] = v;
    }
}

// -------- ablation GEMM v8: m97 geometry, KSPLIT=4 (KSL=1024) --------
// grid 512: ks=bid&3, mi=(bid>>2)&3, nj=bid>>4.
__global__ __launch_bounds__(256) void k_mfma_v8(
    const unsigned short* __restrict__ A, const float* __restrict__ W2,
    const float* __restrict__ h1, unsigned short* __restrict__ partb,
    float* __restrict__ h2part) {
    __shared__ char As[16384];     // 128 rows x 8 chunks x 16B (BK=64 bf16)
    __shared__ char Bs[16384];
    __shared__ float h1s[KSL];     // 4KB
    int bid = blockIdx.x;
    int ks = bid & 3;
    int mi = (bid >> 2) & 3;
    int nj = bid >> 4;             // 0..31
    int t = threadIdx.x;
    int wid = t >> 6, lane = t & 63, lr = lane & 15, lh = lane >> 4;
    int wm = wid >> 1, wn = wid & 1;
    int i0 = mi * 128, j0 = nj * 128;
    int kb = ks * KSL;

    {   // stage h1 slice (1024 floats)
        float4 v = ((const float4*)(h1 + kb))[t];
        *(float4*)&h1s[t * 4] = v;
    }

    bool doh = (mi == 0);
    float hacc[4] = {0.f, 0.f, 0.f, 0.f};
    f32x4 acc[4][4];
    #pragma unroll
    for (int f = 0; f < 4; ++f)
        #pragma unroll
        for (int n = 0; n < 4; ++n) acc[f][n] = (f32x4){0.f, 0.f, 0.f, 0.f};

    for (int kst = 0; kst < KSL; kst += 64) {
        __syncthreads();   // prev compute done reading LDS (publishes h1s iter 0)
        #pragma unroll
        for (int r = 0; r < 4; ++r) {
            int c = t + 256 * r;
            int row = c >> 3, ch = c & 7;
            GLD16(A + (size_t)(i0 + row) * FC + kb + kst + ((ch ^ (row & 7)) * 8),
                  As + (size_t)c * 16);
        }
        #pragma unroll
        for (int r = 0; r < 4; ++r) {
            int c = t + 256 * r;
            int row = c >> 3, ch = c & 7;
            int ko = (ch ^ (row & 7)) * 8;
            const float* wp = W2 + (size_t)(j0 + row) * FC + kb + kst + ko;
            float4 wa = ((const float4*)wp)[0];
            float4 wb = ((const float4*)wp)[1];
            if (doh) {
                hacc[r] += wa.x * h1s[kst + ko + 0] + wa.y * h1s[kst + ko + 1]
                         + wa.z * h1s[kst + ko + 2] + wa.w * h1s[kst + ko + 3]
                         + wb.x * h1s[kst + ko + 4] + wb.y * h1s[kst + ko + 5]
                         + wb.z * h1s[kst + ko + 6] + wb.w * h1s[kst + ko + 7];
            }
            union { bfrag v; unsigned short u[8]; } pk;
            pk.u[0] = f2bf(wa.x); pk.u[1] = f2bf(wa.y);
            pk.u[2] = f2bf(wa.z); pk.u[3] = f2bf(wa.w);
            pk.u[4] = f2bf(wb.x); pk.u[5] = f2bf(wb.y);
            pk.u[6] = f2bf(wb.z); pk.u[7] = f2bf(wb.w);
            *(bfrag*)(Bs + (size_t)c * 16) = pk.v;
        }
        __syncthreads();
        #pragma unroll
        for (int kf = 0; kf < 2; ++kf) {
            bfrag bfr[4];
            #pragma unroll
            for (int n = 0; n < 4; ++n) {
                int br = wn * 64 + n * 16 + lr;
                bfr[n] = *(const bfrag*)(Bs + ((size_t)(br * 8) + ((kf * 4 + lh) ^ (br & 7))) * 16);
            }
            #pragma unroll
            for (int f = 0; f < 4; ++f) {
                int ar = wm * 64 + f * 16 + lr;
                bfrag av = *(const bfrag*)(As + ((size_t)(ar * 8) + ((kf * 4 + lh) ^ (ar & 7))) * 16);
                #pragma unroll
                for (int n = 0; n < 4; ++n)
                    acc[f][n] = __builtin_amdgcn_mfma_f32_16x16x32_bf16(av, bfr[n], acc[f][n], 0, 0, 0);
            }
        }
    }

    if (doh) {
        #pragma unroll
        for (int r = 0; r < 4; ++r) {
            float v = hacc[r];
            v += __shfl_down(v, 4, 8);
            v += __shfl_down(v, 2, 8);
            v += __shfl_down(v, 1, 8);
            if ((t & 7) == 0) h2part[ks * FC + j0 + r * 32 + (t >> 3)] = v;
        }
    }
    unsigned short* pb = partb + (size_t)ks * PSTRIDE;
    #pragma unroll
    for (int f = 0; f < 4; ++f) {
        int row0 = i0 + wm * 64 + f * 16 + lh * 4;
        #pragma unroll
        for (int rr = 0; rr < 4; ++rr)
            #pragma unroll
            for (int n = 0; n < 4; ++n)
                pb[(size_t)(row0 + rr) * FC + j0 + wn * 64 + n * 16 + lr] = f2bf(acc[f][n][rr]);
    }
}

// -------- logits: fused h2(LDS) + W3 gemv --------
__global__ __launch_bounds__(256) void k_logits(
    const float* __restrict__ h2part, const float* __restrict__ b2,
    const float* __restrict__ W3, const float* __restrict__ b3,
    float* __restrict__ logits) {
    __shared__ float h2s[FC];   // 16KB
    __shared__ float red[256];
    int j = blockIdx.x, t = threadIdx.x;
    #pragma unroll
    for (int q = 0; q < 16; ++q) {
        int jj = q * 256 + t;
        float v = b2[jj] + ((h2part[jj] + h2part[FC + jj])
                          + (h2part[2 * FC + jj] + h2part[3 * FC + jj]));
        h2s[jj] = fmaxf(v, 0.f);
    }
    __syncthreads();
    const float4* row = (const float4*)(W3 + (size_t)j * FC);
    const float4* hv = (const float4*)h2s;
    float s = 0.f;
    #pragma unroll
    for (int q = 0; q < 4; ++q) {
        int n = q * 256 + t;
        float4 w = row[n], x = hv[n];
        s += w.x * x.x + w.y * x.y + w.z * x.z + w.w * x.w;
    }
    red[t] = s; __syncthreads();
    if (t < 128) red[t] += red[t + 128]; __syncthreads();
    if (t < 64)  red[t] += red[t + 64];  __syncthreads();
    if (t < 64) {
        float x = red[t];
        for (int off = 32; off > 0; off >>= 1) x += __shfl_down(x, off, 64);
        if (t == 0) logits[j] = x + b3[j];
    }
}

// -------- argmax over logits --------
__global__ void k_argmax(const float* __restrict__ logits, float* __restrict__ clsbase,
                         float* __restrict__ dout_cls) {
    int t = threadIdx.x;
    float best = -INFINITY; int bi = NCLS;
    for (int n = t; n < NCLS; n += 256) {
        float v = logits[n];
        if (v > best || (v == best && n < bi)) { best = v; bi = n; }
    }
    __shared__ float bv[256]; __shared__ int bidx[256];
    bv[t] = best; bidx[t] = bi; __syncthreads();
    for (int o = 128; o > 0; o >>= 1) {
        if (t < o) {
            float v2 = bv[t + o]; int i2 = bidx[t + o];
            if (v2 > bv[t] || (v2 == bv[t] && i2 < bidx[t])) { bv[t] = v2; bidx[t] = i2; }
        }
        __syncthreads();
    }
    if (t == 0) { clsbase[0] = (float)bidx[0]; clsbase[1] = bv[0]; *dout_cls = (float)bidx[0]; }
}

// -------- per-ablation class logit from bf16 k-partials + alpha --------
__global__ __launch_bounds__(256) void k_alpha_b(
    const unsigned short* __restrict__ partb, const float* __restrict__ b2,
    const float* __restrict__ W3, const float* __restrict__ b3,
    const float* __restrict__ clsbase, float* __restrict__ alpha) {
    int i = blockIdx.x, t = threadIdx.x;
    int cls = (int)clsbase[0]; float base = clsbase[1];
    const float* w3r = W3 + (size_t)cls * FC;
    float s = 0.f;
    #pragma unroll
    for (int q = 0; q < 2; ++q) {
        int jj = (q * 256 + t) * 8;
        float acc8[8];
        #pragma unroll
        for (int e = 0; e < 8; ++e) acc8[e] = b2[jj + e];
        #pragma unroll
        for (int p = 0; p < KSPLIT; ++p) {
            uint4 pv = *(const uint4*)(partb + (size_t)p * PSTRIDE + (size_t)i * FC + jj);
            #pragma unroll
            for (int e = 0; e < 4; ++e) {
                unsigned a = ((const unsigned*)&pv)[e];
                acc8[e * 2]     += __uint_as_float(a << 16);
                acc8[e * 2 + 1] += __uint_as_float(a & 0xFFFF0000u);
            }
        }
        #pragma unroll
        for (int e = 0; e < 8; ++e) s += fmaxf(acc8[e], 0.f) * w3r[jj + e];
    }
    __shared__ float red[256];
    red[t] = s; __syncthreads();
    if (t < 128) red[t] += red[t + 128]; __syncthreads();
    if (t < 64)  red[t] += red[t + 64];  __syncthreads();
    if (t < 64) {
        float x = red[t];
        for (int off = 32; off > 0; off >>= 1) x += __shfl_down(x, off, 64);
        if (t == 0) alpha[i] = (base - (x + b3[cls])) / base;
    }
}

// ======== fallback fp32 path (ws too small) ========
template <bool RELU>
__global__ void k_gemv4096(const float* __restrict__ M, const float* __restrict__ v,
                           const float* __restrict__ bias, float* __restrict__ out) {
    int j = blockIdx.x, t = threadIdx.x;
    const float4* row = (const float4*)(M + (size_t)j * FC);
    const float4* vv = (const float4*)v;
    float s = 0.f;
    #pragma unroll
    for (int q = 0; q < 4; ++q) {
        int n = q * 256 + t;
        float4 w = row[n], x = vv[n];
        s += w.x * x.x + w.y * x.y + w.z * x.z + w.w * x.w;
    }
    __shared__ float red[256];
    red[t] = s; __syncthreads();
    if (t < 128) red[t] += red[t + 128]; __syncthreads();
    if (t < 64)  red[t] += red[t + 64];  __syncthreads();
    if (t < 64) {
        float x = red[t];
        for (int off = 32; off > 0; off >>= 1) x += __shfl_down(x, off, 64);
        if (t == 0) { float r2 = bias[j] + x; out[j] = RELU ? fmaxf(r2, 0.f) : r2; }
    }
}

__global__ __launch_bounds__(256) void k_gemm_abl(
    const float* __restrict__ Dt, const float* __restrict__ h1pre,
    const float* __restrict__ W2, const float* __restrict__ b2,
    const float* __restrict__ W3, const float* __restrict__ clsbase,
    float* __restrict__ logit_part) {
    int mi = blockIdx.x, nj = blockIdx.y, t = threadIdx.x;
    int tx = t & 15, ty = t >> 4;
    int i0 = mi * 64, j0 = nj * 64;
    __shared__ float As2[16][64];
    __shared__ float Bs2[16][65];
    float acc[4][4] = {};
    for (int k0 = 0; k0 < FC; k0 += 16) {
        #pragma unroll
        for (int r = 0; r < 4; ++r) {
            int e = t + 256 * r; int kk = e >> 6, ii = e & 63;
            As2[kk][ii] = fmaxf(h1pre[k0 + kk] - Dt[(size_t)(k0 + kk) * CCH + i0 + ii], 0.f);
        }
        {
            int jj = t >> 2, kks = (t & 3) * 4;
            const float4 wv = *(const float4*)(W2 + (size_t)(j0 + jj) * FC + k0 + kks);
            Bs2[kks + 0][jj] = wv.x; Bs2[kks + 1][jj] = wv.y;
            Bs2[kks + 2][jj] = wv.z; Bs2[kks + 3][jj] = wv.w;
        }
        __syncthreads();
        #pragma unroll
        for (int kk = 0; kk < 16; ++kk) {
            float4 a4 = *(const float4*)&As2[kk][tx * 4];
            float av[4] = {a4.x, a4.y, a4.z, a4.w};
            float bv[4] = {Bs2[kk][ty * 4 + 0], Bs2[kk][ty * 4 + 1],
                           Bs2[kk][ty * 4 + 2], Bs2[kk][ty * 4 + 3]};
            #pragma unroll
            for (int a = 0; a < 4; ++a)
                #pragma unroll
                for (int bb = 0; bb < 4; ++bb)
                    acc[a][bb] = fmaf(av[a], bv[bb], acc[a][bb]);
        }
        __syncthreads();
    }
    int cls = (int)clsbase[0];
    const float* w3r = W3 + (size_t)cls * FC;
    float prt[4] = {0.f, 0.f, 0.f, 0.f};
    #pragma unroll
    for (int bb = 0; bb < 4; ++bb) {
        int j2 = j0 + ty * 4 + bb;
        float b2v = b2[j2], w3 = w3r[j2];
        #pragma unroll
        for (int a = 0; a < 4; ++a) prt[a] = fmaf(fmaxf(acc[a][bb] + b2v, 0.f), w3, prt[a]);
    }
    __shared__ float red2[16][68];
    #pragma unroll
    for (int a = 0; a < 4; ++a) red2[ty][tx * 4 + a] = prt[a];
    __syncthreads();
    if (t < 64) {
        float s = 0.f;
        #pragma unroll
        for (int q = 0; q < 16; ++q) s += red2[q][t];
        logit_part[nj * CCH + i0 + t] = s;
    }
}

__global__ void k_alpha_fb(const float* __restrict__ logit_part, const float* __restrict__ b3,
                           const float* __restrict__ clsbase, float* __restrict__ alpha) {
    int t = blockIdx.x * 256 + threadIdx.x;
    if (t >= CCH) return;
    int cls = (int)clsbase[0]; float base = clsbase[1];
    float s = 0.f;
    for (int q = 0; q < 64; ++q) s += logit_part[q * CCH + t];
    alpha[t] = (base - (s + b3[cls])) / base;
}

// -------- fused weighted-map + bilinear 14->224 + relu + min/max --------
__global__ void k_resize2(const float* __restrict__ alpha, const float* __restrict__ act,
                          float* __restrict__ out, int* __restrict__ minmax) {
    __shared__ float sA[CCH];
    __shared__ float sW[196];
    int t = threadIdx.x;
    for (int i = t; i < CCH; i += 256) sA[i] = alpha[i];
    __syncthreads();
    if (t < 196) {
        float s = 0.f;
        for (int c = 0; c < CCH; ++c) s = fmaf(sA[c], act[c * 196 + t], s);
        sW[t] = s;
    }
    __syncthreads();
    int pix = blockIdx.x * 256 + t;
    int y = pix / OW, x = pix % OW;
    float uy = (y + 0.5f) * 0.0625f - 0.5f;
    float ux = (x + 0.5f) * 0.0625f - 0.5f;
    float y0f = floorf(uy), x0f = floorf(ux);
    float fy = uy - y0f, fx = ux - x0f;
    int y0 = (int)y0f, x0 = (int)x0f;
    int y0c = min(max(y0, 0), 13), y1c = min(max(y0 + 1, 0), 13);
    int x0c = min(max(x0, 0), 13), x1c = min(max(x0 + 1, 0), 13);
    float v00 = sW[y0c * 14 + x0c], v01 = sW[y0c * 14 + x1c];
    float v10 = sW[y1c * 14 + x0c], v11 = sW[y1c * 14 + x1c];
    float v0 = v00 + (v01 - v00) * fx;
    float v1 = v10 + (v11 - v10) * fx;
    float v = v0 + (v1 - v0) * fy;
    float f = fmaxf(v, 0.f);
    out[pix] = f;
    __shared__ float rmn[256], rmx[256];
    rmn[t] = f; rmx[t] = f; __syncthreads();
    for (int o = 128; o > 0; o >>= 1) {
        if (t < o) { rmn[t] = fminf(rmn[t], rmn[t + o]); rmx[t] = fmaxf(rmx[t], rmx[t + o]); }
        __syncthreads();
    }
    if (t == 0) {
        atomicMin(&minmax[0], __float_as_int(rmn[0]));
        atomicMax(&minmax[1], __float_as_int(rmx[0]));
    }
}

__global__ void k_norm(float* __restrict__ out, const int* __restrict__ minmax) {
    float mn = __int_as_float(minmax[0]);
    float mx = __int_as_float(minmax[1]);
    int pix = blockIdx.x * 256 + threadIdx.x;
    if (mx != mn) out[pix] = (out[pix] - mn) / (mx - mn);
}

extern "C" void kernel_launch(void* const* d_in, const int* in_sizes, int n_in,
                              void* d_out, int out_size, void* d_ws, size_t ws_size,
                              hipStream_t stream) {
    const float* act = (const float*)d_in[0];
    const float* W1  = (const float*)d_in[1];
    const float* b1  = (const float*)d_in[2];
    const float* W2  = (const float*)d_in[3];
    const float* b2  = (const float*)d_in[4];
    const float* W3  = (const float*)d_in[5];
    const float* b3  = (const float*)d_in[6];
    float* out = (float*)d_out;
    float* ws = (float*)d_ws;
    const bool fast = (ws_size >= WS_NEED_BYTES);

    k_maxpool<<<98, 256, 0, stream>>>(act, ws);
    k_phi8<<<4096, 256, 0, stream>>>(W1, ws + WS_MP, b1, ws + WS_DT,
                                     ws + WS_H1PRE, ws + WS_H1);
    if (fast) {
        k_abuild<<<dim3(64, 8), 256, 0, stream>>>(ws + WS_DT, ws + WS_H1PRE,
                                                  (unsigned short*)(ws + WS_A));
        k_mfma_v8<<<512, 256, 0, stream>>>(
            (const unsigned short*)(ws + WS_A), W2, ws + WS_H1,
            (unsigned short*)(ws + WS_PARTB), ws + WS_H2PART);
        k_logits<<<NCLS, 256, 0, stream>>>(ws + WS_H2PART, b2, W3, b3, ws + WS_LOGITS);
        k_argmax<<<1, 256, 0, stream>>>(ws + WS_LOGITS, ws + WS_CLSBASE, out + 50176);
        k_alpha_b<<<CCH, 256, 0, stream>>>((const unsigned short*)(ws + WS_PARTB), b2,
                                           W3, b3, ws + WS_CLSBASE, ws + WS_ALPHA);
    } else {
        k_gemv4096<true><<<4096, 256, 0, stream>>>(W2, ws + WS_H1, b2, ws + WS_H2);
        k_gemv4096<false><<<1000, 256, 0, stream>>>(W3, ws + WS_H2, b3, ws + WS_LOGITS);
        k_argmax<<<1, 256, 0, stream>>>(ws + WS_LOGITS, ws + WS_CLSBASE, out + 50176);
        k_gemm_abl<<<dim3(8, 64), 256, 0, stream>>>(ws + WS_DT, ws + WS_H1PRE, W2, b2,
                                                    W3, ws + WS_CLSBASE, ws + WS_LOGPART);
        k_alpha_fb<<<2, 256, 0, stream>>>(ws + WS_LOGPART, b3, ws + WS_CLSBASE,
                                          ws + WS_ALPHA);
    }
    k_resize2<<<196, 256, 0, stream>>>(ws + WS_ALPHA, act, out, (int*)(ws + WS_MINMAX));
    k_norm<<<196, 256, 0, stream>>>(out, (const int*)(ws + WS_MINMAX));
}